// Round 10
// baseline (67.023 us; speedup 1.0000x reference)
//
#include <hip/hip_runtime.h>

#define L2E  1.4426950408889634f
#define LN2f 0.6931471805599453f

template<int CTRL>
__device__ __forceinline__ float dppf(float x) {
  int r = __builtin_amdgcn_update_dpp(0, __builtin_bit_cast(int, x), CTRL, 0xF, 0xF, true);
  return __builtin_bit_cast(float, r);
}
template<int CTRL>
__device__ __forceinline__ int dppi(int x) {
  return __builtin_amdgcn_update_dpp(0, x, CTRL, 0xF, 0xF, true);
}

// max over the 16-lane group via DPP butterfly (verified R2/R4/R5/R8/R9, absmax 0)
__device__ __forceinline__ float bflymax16(float x) {
  x = fmaxf(x, dppf<0xB1>(x));    // lane^1
  x = fmaxf(x, dppf<0x4E>(x));    // lane^2
  x = fmaxf(x, dppf<0x141>(x));   // lane^7
  x = fmaxf(x, dppf<0x140>(x));   // lane^15
  return x;
}

// Fused rotate-and-dot (verified R4..R9): tot_j = sum_r rot_r(shv)_j * Wror[r]_j
#define DOT(shv, tot) {                                   \
    float t0_ = (shv) * Wror[0], t1_ = 0.f, t2_ = 0.f, t3_ = 0.f; \
    t1_ = fmaf(dppf<0x121>(shv), Wror[1],  t1_);          \
    t2_ = fmaf(dppf<0x122>(shv), Wror[2],  t2_);          \
    t3_ = fmaf(dppf<0x123>(shv), Wror[3],  t3_);          \
    t0_ = fmaf(dppf<0x124>(shv), Wror[4],  t0_);          \
    t1_ = fmaf(dppf<0x125>(shv), Wror[5],  t1_);          \
    t2_ = fmaf(dppf<0x126>(shv), Wror[6],  t2_);          \
    t3_ = fmaf(dppf<0x127>(shv), Wror[7],  t3_);          \
    t0_ = fmaf(dppf<0x128>(shv), Wror[8],  t0_);          \
    t1_ = fmaf(dppf<0x129>(shv), Wror[9],  t1_);          \
    t2_ = fmaf(dppf<0x12A>(shv), Wror[10], t2_);          \
    t3_ = fmaf(dppf<0x12B>(shv), Wror[11], t3_);          \
    t0_ = fmaf(dppf<0x12C>(shv), Wror[12], t0_);          \
    t1_ = fmaf(dppf<0x12D>(shv), Wror[13], t1_);          \
    t2_ = fmaf(dppf<0x12E>(shv), Wror[14], t2_);          \
    t3_ = fmaf(dppf<0x12F>(shv), Wror[15], t3_);          \
    tot = (t0_ + t1_) + (t2_ + t3_); }

#define VWAIT(N) do { asm volatile("s_waitcnt vmcnt(" #N ")" ::: "memory"); \
                      __builtin_amdgcn_sched_barrier(0); } while (0)
#define SBAR()   __builtin_amdgcn_sched_barrier(0)

// fwd step: v_t = mask_t ? diag(p_t)·W^T·v : v   (math verified R5/R8/R9)
#define FSTEP(OWN, MM, EAC, emit, yi, RN) do {                        \
    const float e_ = (emit); const int yi_ = (yi);                    \
    const float p_ = exp2f(e_ * L2E);                                 \
    float tot_; DOT(OWN, tot_);                                       \
    const float cand_ = tot_ * p_;                                    \
    OWN = (yi_ != 15) ? cand_ : OWN;                                  \
    EAC += (yi_ == jm) ? e_ : 0.f;                                    \
    if (RN) { const float m_ = bflymax16(OWN);                        \
      OWN *= __builtin_amdgcn_rcpf(m_); MM += log2f(m_); }            \
  } while (0)

// bwd step: u_{t-1} = mask_t ? W·(p_t ∘ u_t) : u_t
#define BSTEP(OWN, MM, EAC, emit, yi, RN) do {                        \
    const float e_ = (emit); const int yi_ = (yi);                    \
    const float p_ = exp2f(e_ * L2E);                                 \
    const float sh_ = OWN * p_;                                       \
    float tot_; DOT(sh_, tot_);                                       \
    OWN = (yi_ != 15) ? tot_ : OWN;                                   \
    EAC += (yi_ == jm) ? e_ : 0.f;                                    \
    if (RN) { const float m_ = bflymax16(OWN);                        \
      OWN *= __builtin_amdgcn_rcpf(m_); MM += log2f(m_); }            \
  } while (0)

// batch issue, fwd: 8 emits (+60B stride) + 2 int4 y loads; offsets advance
#define FISSV(EBF, Y0, Y1, EV, YV) do {                               \
    EBF[0] = *(const float*)(eub + EV);                               \
    EBF[1] = *(const float*)(eub + EV + 60);                          \
    EBF[2] = *(const float*)(eub + EV + 120);                         \
    EBF[3] = *(const float*)(eub + EV + 180);                         \
    EBF[4] = *(const float*)(eub + EV + 240);                         \
    EBF[5] = *(const float*)(eub + EV + 300);                         \
    EBF[6] = *(const float*)(eub + EV + 360);                         \
    EBF[7] = *(const float*)(eub + EV + 420);                         \
    Y0 = *(const int4*)(yub + YV);                                    \
    Y1 = *(const int4*)(yub + YV + 16);                               \
    EV += 480; YV += 32;                                              \
  } while (0)

// batch issue, bwd: descending t; EV at t_hi, YV at (t_hi-7)*4
#define BISSV(EBF, Y0, Y1, EV, YV) do {                               \
    EBF[0] = *(const float*)(eub + EV);                               \
    EBF[1] = *(const float*)(eub + EV - 60);                          \
    EBF[2] = *(const float*)(eub + EV - 120);                         \
    EBF[3] = *(const float*)(eub + EV - 180);                         \
    EBF[4] = *(const float*)(eub + EV - 240);                         \
    EBF[5] = *(const float*)(eub + EV - 300);                         \
    EBF[6] = *(const float*)(eub + EV - 360);                         \
    EBF[7] = *(const float*)(eub + EV - 420);                         \
    Y0 = *(const int4*)(yub + YV);                                    \
    Y1 = *(const int4*)(yub + YV + 16);                               \
    EV -= 480; YV -= 32;                                              \
  } while (0)

// consume one batch-pair: groups A and B interleaved step-by-step (the ILP lever)
#define PFCONS(EA, YA0, YA1, EBB, YB0, YB1) do {                                  \
    FSTEP(ownA,MA,eaccA, EA[0], (YA0).x, 0); FSTEP(ownB,MB,eaccB, EBB[0], (YB0).x, 0); \
    FSTEP(ownA,MA,eaccA, EA[1], (YA0).y, 0); FSTEP(ownB,MB,eaccB, EBB[1], (YB0).y, 0); \
    FSTEP(ownA,MA,eaccA, EA[2], (YA0).z, 0); FSTEP(ownB,MB,eaccB, EBB[2], (YB0).z, 0); \
    FSTEP(ownA,MA,eaccA, EA[3], (YA0).w, 0); FSTEP(ownB,MB,eaccB, EBB[3], (YB0).w, 0); \
    FSTEP(ownA,MA,eaccA, EA[4], (YA1).x, 0); FSTEP(ownB,MB,eaccB, EBB[4], (YB1).x, 0); \
    FSTEP(ownA,MA,eaccA, EA[5], (YA1).y, 0); FSTEP(ownB,MB,eaccB, EBB[5], (YB1).y, 0); \
    FSTEP(ownA,MA,eaccA, EA[6], (YA1).z, 0); FSTEP(ownB,MB,eaccB, EBB[6], (YB1).z, 0); \
    FSTEP(ownA,MA,eaccA, EA[7], (YA1).w, 1); FSTEP(ownB,MB,eaccB, EBB[7], (YB1).w, 1); \
  } while (0)

#define PBCONS(EA, YA0, YA1, EBB, YB0, YB1) do {                                  \
    BSTEP(ownA,MA,eaccA, EA[0], (YA1).w, 0); BSTEP(ownB,MB,eaccB, EBB[0], (YB1).w, 0); \
    BSTEP(ownA,MA,eaccA, EA[1], (YA1).z, 0); BSTEP(ownB,MB,eaccB, EBB[1], (YB1).z, 0); \
    BSTEP(ownA,MA,eaccA, EA[2], (YA1).y, 0); BSTEP(ownB,MB,eaccB, EBB[2], (YB1).y, 0); \
    BSTEP(ownA,MA,eaccA, EA[3], (YA1).x, 0); BSTEP(ownB,MB,eaccB, EBB[3], (YB1).x, 0); \
    BSTEP(ownA,MA,eaccA, EA[4], (YA0).w, 0); BSTEP(ownB,MB,eaccB, EBB[4], (YB0).w, 0); \
    BSTEP(ownA,MA,eaccA, EA[5], (YA0).z, 0); BSTEP(ownB,MB,eaccB, EBB[5], (YB0).z, 0); \
    BSTEP(ownA,MA,eaccA, EA[6], (YA0).y, 0); BSTEP(ownB,MB,eaccB, EBB[6], (YB0).y, 0); \
    BSTEP(ownA,MA,eaccA, EA[7], (YA0).x, 1); BSTEP(ownB,MB,eaccB, EBB[7], (YB0).x, 1); \
  } while (0)

__global__ __launch_bounds__(256, 1)
void crf_ilp(const float* __restrict__ logits, const int* __restrict__ yg,
             const float* __restrict__ trans, float* __restrict__ out) {
  __shared__ float Tl[240];
  __shared__ float comb[16][2][16];
  __shared__ float pathE[16][2];
  __shared__ float transS[16];
  __shared__ float blks[16];

  const int tid = threadIdx.x;
  if (tid < 225) Tl[tid] = trans[tid];
  __syncthreads();

  // wave-uniform bases; all per-lane addressing via 32-bit byte offsets
  const char* eub = (const char*)logits + (size_t)blockIdx.x * (16 * 30720);
  const char* yub = (const char*)yg + (size_t)blockIdx.x * (16 * 2048);

  // ---- transition part of path score (16 seqs, 16 threads each) ----
  {
    const int sq = tid >> 4, l16 = tid & 15;
    const int* ys = (const int*)(yub + sq * 2048);
    float acc = 0.f;
    #pragma unroll
    for (int m = 0; m < 32; ++m) {
      const int t = 1 + l16 + 16 * m;
      if (t < 512) {
        const int yc = ys[t], yp = ys[t - 1];
        if (yc < 15 && yp < 15) acc += Tl[yp * 15 + yc];
      }
    }
    #pragma unroll
    for (int k = 1; k < 16; k <<= 1) acc += __shfl_xor(acc, k, 16);
    if (l16 == 0) transS[sq] = acc;
  }

  // ---- wave -> (direction, 2 chain-groups of 4 seqs each) ----
  const int wave = tid >> 6, lane = tid & 63;
  const int j = lane & 15;
  const int c = lane >> 4;                    // chain slot 0..3
  const bool isFwd = (wave >> 1) == 0;
  const int half = wave & 1;
  const int sA = half * 8 + c;                // group A local seq
  const int sB = half * 8 + 4 + c;            // group B local seq
  const int jj = (j < 15) ? j : 14;
  const int jm = (j < 15) ? j : 255;

  // Wror (direction-proof construction, verified R4..R9); shared by A and B
  float Wror[16];
  Wror[0] = (j < 15) ? exp2f(Tl[j * 16] * L2E) : 0.f;
#define SETW(R) { const int s_ = dppi<0x120 + (R)>(j);                  \
    const bool v_ = (j < 15) && (s_ < 15);                              \
    const int ix_ = isFwd ? s_ * 15 + j : j * 15 + s_;                  \
    Wror[R] = v_ ? exp2f(Tl[v_ ? ix_ : 0] * L2E) : 0.f; }
  SETW(1)  SETW(2)  SETW(3)  SETW(4)  SETW(5)
  SETW(6)  SETW(7)  SETW(8)  SETW(9)  SETW(10)
  SETW(11) SETW(12) SETW(13) SETW(14) SETW(15)
#undef SETW
  #pragma unroll
  for (int r = 0; r < 16; ++r) asm volatile("" : "+v"(Wror[r]));  // pin (R5 win)

  float ownA, MA, eaccA, ownB, MB, eaccB;
  float ebXA[8], ebYA[8], ebXB[8], ebYB[8];
  int4 yXA0, yXA1, yYA0, yYA1, yXB0, yXB1, yYB0, yYB1;

  if (isFwd) {
    int evA = sA * 30720 + jj * 4, yvA = sA * 2048;
    int evB = sB * 30720 + jj * 4, yvB = sB * 2048;
    // prologue direct loads: t=0..7 both groups
    float e0A[8], e0B[8];
    #pragma unroll
    for (int i = 0; i < 8; ++i) {
      e0A[i] = *(const float*)(eub + evA + i * 60);
      e0B[i] = *(const float*)(eub + evB + i * 60);
    }
    const int4 yPA0 = *(const int4*)(yub + yvA);
    const int4 yPA1 = *(const int4*)(yub + yvA + 16);
    const int4 yPB0 = *(const int4*)(yub + yvB);
    const int4 yPB1 = *(const int4*)(yub + yvB + 16);
    evA += 480; yvA += 32; evB += 480; yvB += 32;
    FISSV(ebXA, yXA0, yXA1, evA, yvA);   // A b0: t=8..15
    FISSV(ebXB, yXB0, yXB1, evB, yvB);   // B b0
    FISSV(ebYA, yYA0, yYA1, evA, yvA);   // A b1: t=16..23
    FISSV(ebYB, yYB0, yYB1, evB, yvB);   // B b1
    SBAR();

    // init (t=0) + 7 prologue steps (t=1..7), interleaved A/B
    const float a0A = e0A[0], a0B = e0B[0];
    eaccA = (yPA0.x == jm) ? a0A : 0.f;
    eaccB = (yPB0.x == jm) ? a0B : 0.f;
    const float AA = (j < 15) ? a0A * L2E : -1.0e30f;
    const float AB = (j < 15) ? a0B * L2E : -1.0e30f;
    const float M0A = bflymax16(AA), M0B = bflymax16(AB);
    ownA = exp2f(AA - M0A); MA = M0A;
    ownB = exp2f(AB - M0B); MB = M0B;
    FSTEP(ownA,MA,eaccA, e0A[1], yPA0.y, 0); FSTEP(ownB,MB,eaccB, e0B[1], yPB0.y, 0);
    FSTEP(ownA,MA,eaccA, e0A[2], yPA0.z, 0); FSTEP(ownB,MB,eaccB, e0B[2], yPB0.z, 0);
    FSTEP(ownA,MA,eaccA, e0A[3], yPA0.w, 0); FSTEP(ownB,MB,eaccB, e0B[3], yPB0.w, 0);
    FSTEP(ownA,MA,eaccA, e0A[4], yPA1.x, 0); FSTEP(ownB,MB,eaccB, e0B[4], yPB1.x, 0);
    FSTEP(ownA,MA,eaccA, e0A[5], yPA1.y, 0); FSTEP(ownB,MB,eaccB, e0B[5], yPB1.y, 0);
    FSTEP(ownA,MA,eaccA, e0A[6], yPA1.z, 0); FSTEP(ownB,MB,eaccB, e0B[6], yPB1.z, 0);
    FSTEP(ownA,MA,eaccA, e0A[7], yPA1.w, 1); FSTEP(ownB,MB,eaccB, e0B[7], yPB1.w, 1);

    // main: 31 batches (t=8..255), double-buffered pairs, counted vmcnt
    #pragma unroll 1
    for (int k = 0; k < 14; ++k) {
      VWAIT(20); PFCONS(ebXA,yXA0,yXA1, ebXB,yXB0,yXB1);
      FISSV(ebXA,yXA0,yXA1,evA,yvA); FISSV(ebXB,yXB0,yXB1,evB,yvB); SBAR();
      VWAIT(20); PFCONS(ebYA,yYA0,yYA1, ebYB,yYB0,yYB1);
      FISSV(ebYA,yYA0,yYA1,evA,yvA); FISSV(ebYB,yYB0,yYB1,evB,yvB); SBAR();
    }
    VWAIT(20); PFCONS(ebXA,yXA0,yXA1, ebXB,yXB0,yXB1);          // b28
    FISSV(ebXA,yXA0,yXA1,evA,yvA); FISSV(ebXB,yXB0,yXB1,evB,yvB); SBAR();  // issue b30
    VWAIT(20); PFCONS(ebYA,yYA0,yYA1, ebYB,yYB0,yYB1);          // b29
    VWAIT(0);  PFCONS(ebXA,yXA0,yXA1, ebXB,yXB0,yXB1);          // b30 (t=248..255)
  } else {
    int evA = sA * 30720 + jj * 4 + 511 * 60, yvA = sA * 2048 + 504 * 4;
    int evB = sB * 30720 + jj * 4 + 511 * 60, yvB = sB * 2048 + 504 * 4;
    ownA = (j < 15) ? 1.f : 0.f; MA = 0.f; eaccA = 0.f;
    ownB = (j < 15) ? 1.f : 0.f; MB = 0.f; eaccB = 0.f;
    BISSV(ebXA, yXA0, yXA1, evA, yvA);   // A b0: t=511..504
    BISSV(ebXB, yXB0, yXB1, evB, yvB);
    BISSV(ebYA, yYA0, yYA1, evA, yvA);   // A b1: t=503..496
    BISSV(ebYB, yYB0, yYB1, evB, yvB);
    SBAR();
    #pragma unroll 1
    for (int k = 0; k < 15; ++k) {
      VWAIT(20); PBCONS(ebXA,yXA0,yXA1, ebXB,yXB0,yXB1);
      BISSV(ebXA,yXA0,yXA1,evA,yvA); BISSV(ebXB,yXB0,yXB1,evB,yvB); SBAR();
      VWAIT(20); PBCONS(ebYA,yYA0,yYA1, ebYB,yYB0,yYB1);
      BISSV(ebYA,yYA0,yYA1,evA,yvA); BISSV(ebYB,yYB0,yYB1,evB,yvB); SBAR();
    }
    VWAIT(20); PBCONS(ebXA,yXA0,yXA1, ebXB,yXB0,yXB1);          // b30 (t=271..264)
    VWAIT(0);  PBCONS(ebYA,yYA0,yYA1, ebYB,yYB0,yYB1);          // b31 (t=263..256)
  }

  const int dir = isFwd ? 0 : 1;
  if (j < 15) {
    comb[sA][dir][j] = MA + log2f(ownA);
    comb[sB][dir][j] = MB + log2f(ownB);
  }
  #pragma unroll
  for (int k = 1; k < 16; k <<= 1) {
    eaccA += __shfl_xor(eaccA, k, 16);
    eaccB += __shfl_xor(eaccB, k, 16);
  }
  if (j == 0) { pathE[sA][dir] = eaccA; pathE[sB][dir] = eaccB; }

  __syncthreads();

  // ---- per-sequence combine: logZ = lse_i(log v_255[i] + log u_255[i]) ----
  if (tid < 16) {
    float mx = -3.0e38f; float s[15];
    #pragma unroll
    for (int i = 0; i < 15; ++i) {
      s[i] = comb[tid][0][i] + comb[tid][1][i];
      mx = fmaxf(mx, s[i]);
    }
    float sum = 0.f;
    #pragma unroll
    for (int i = 0; i < 15; ++i) sum += exp2f(s[i] - mx);
    const float logZ = (mx + log2f(sum)) * LN2f;
    const float path = pathE[tid][0] + pathE[tid][1] + transS[tid];
    float nll = logZ - path;
    nll = fminf(fmaxf(nll, 0.f), 1000000.f);
    blks[tid] = nll;
  }
  __syncthreads();
  if (tid == 0) {
    float tot = 0.f;
    #pragma unroll
    for (int i = 0; i < 16; ++i) tot += blks[i];
    atomicAdd(out, tot * (1.0f / 4096.0f));
  }
}

extern "C" void kernel_launch(void* const* d_in, const int* in_sizes, int n_in,
                              void* d_out, int out_size, void* d_ws, size_t ws_size,
                              hipStream_t stream) {
  const float* logits = (const float*)d_in[0];   // (4096, 512, 15) f32
  const int*   y      = (const int*)d_in[1];     // (4096, 512) i32
  const float* trans  = (const float*)d_in[2];   // (15, 15) f32
  float* out = (float*)d_out;

  hipMemsetAsync(out, 0, sizeof(float), stream);

  const int B = in_sizes[1] / 512;               // 4096
  crf_ilp<<<dim3(B / 16), dim3(256), 0, stream>>>(logits, y, trans, out);
}